// Round 9
// baseline (510.773 us; speedup 1.0000x reference)
//
#include <hip/hip_runtime.h>
#include <math.h>

#define N_GRID 65160
#define N_MESH 40962
#define N_TOT  106122
#define NE     521280
#define IN_CH  96
#define HID    256
#define OUT_CH 96

// ---------------- concat + transpose: (96,N) channel-major -> (N,96) node-major ----------------
__global__ void k_concat_transpose(const float* __restrict__ xg, const float* __restrict__ xm,
                                   float* __restrict__ h) {
  __shared__ float tile[IN_CH][65];
  int base = blockIdx.x * 64;
  int t = threadIdx.x;
#pragma unroll
  for (int it = 0; it < 24; ++it) {
    int lin = t + it * 256;            // 0..6143 over 96x64
    int c  = lin >> 6;
    int n0 = lin & 63;
    int n = base + n0;
    float v = 0.f;
    if (n < N_TOT) {
      v = (n < N_GRID) ? xg[(size_t)c * N_GRID + n]
                       : xm[(size_t)c * N_MESH + (n - N_GRID)];
    }
    tile[c][n0] = v;
  }
  __syncthreads();
#pragma unroll
  for (int it = 0; it < 24; ++it) {
    int lin = t + it * 256;
    int c  = lin % 96;
    int n0 = lin / 96;
    int n = base + n0;
    if (n < N_TOT) h[(size_t)n * IN_CH + c] = tile[c][n0];
  }
}

// ---------------- CSR build ----------------
__global__ void k_zeroi(int* __restrict__ p, int n) {
  int i = blockIdx.x * 256 + threadIdx.x;
  if (i < n) p[i] = 0;
}
__global__ void k_seti(int* __restrict__ p, int v) { *p = v; }

__global__ void k_hist(const int* __restrict__ dst, int* __restrict__ deg) {
  int e = blockIdx.x * 256 + threadIdx.x;
  if (e < NE) atomicAdd(&deg[dst[e]], 1);
}

__global__ void k_blocksum(const int* __restrict__ deg, int* __restrict__ bsum, int n) {
  __shared__ int s[256];
  int i = blockIdx.x * 256 + threadIdx.x;
  s[threadIdx.x] = (i < n) ? deg[i] : 0;
  __syncthreads();
  for (int st = 128; st > 0; st >>= 1) {
    if (threadIdx.x < st) s[threadIdx.x] += s[threadIdx.x + st];
    __syncthreads();
  }
  if (threadIdx.x == 0) bsum[blockIdx.x] = s[0];
}

__global__ void k_scanbsum(int* __restrict__ bsum, int nb) {   // single block, 512 thr
  __shared__ int s[512];
  int t = threadIdx.x;
  int v = (t < nb) ? bsum[t] : 0;
  s[t] = v;
  __syncthreads();
  for (int off = 1; off < 512; off <<= 1) {
    int x = (t >= off) ? s[t - off] : 0;
    __syncthreads();
    s[t] += x;
    __syncthreads();
  }
  if (t < nb) bsum[t] = s[t] - v;   // exclusive
}

__global__ void k_offsets(const int* __restrict__ deg, const int* __restrict__ bsum,
                          int* __restrict__ off, int* __restrict__ cur, int n) {
  __shared__ int s[256];
  int i = blockIdx.x * 256 + threadIdx.x;
  int v = (i < n) ? deg[i] : 0;
  s[threadIdx.x] = v;
  __syncthreads();
  for (int o = 1; o < 256; o <<= 1) {
    int x = (threadIdx.x >= o) ? s[threadIdx.x - o] : 0;
    __syncthreads();
    s[threadIdx.x] += x;
    __syncthreads();
  }
  if (i < n) {
    int e = bsum[blockIdx.x] + s[threadIdx.x] - v;
    off[i] = e;
    cur[i] = e;
  }
}

__global__ void k_fillcsr(const int* __restrict__ src, const int* __restrict__ dst,
                          int* __restrict__ cur, int* __restrict__ csrc) {
  int e = blockIdx.x * 256 + threadIdx.x;
  if (e < NE) {
    int p = atomicAdd(&cur[dst[e]], 1);
    csrc[p] = src[e];
  }
}

__global__ void k_dinv(const int* __restrict__ deg, float* __restrict__ dinv, int n) {
  int i = blockIdx.x * 256 + threadIdx.x;
  if (i < n) dinv[i] = rsqrtf(1.0f + (float)deg[i]);
}

// ---------------- gather aggregation (no atomics), 4-edge unrolled (outstanding-load MLP) ----------------
__global__ void k_gather96(const int* __restrict__ off, const int* __restrict__ csrc,
                           const float* __restrict__ dinv, const float* __restrict__ h,
                           float* __restrict__ agg) {
  int i = blockIdx.x * 256 + threadIdx.x;
  if (i >= N_TOT * 24) return;
  int n = i / 24;
  int c4 = (i % 24) << 2;
  float di = dinv[n];
  float4 v = *(const float4*)(h + (size_t)n * 96 + c4);
  float w0 = di * di;
  float4 acc = make_float4(v.x * w0, v.y * w0, v.z * w0, v.w * w0);
  int e0 = off[n], e1 = off[n + 1];
  int e = e0;
  for (; e + 3 < e1; e += 4) {
    int s0 = csrc[e], s1 = csrc[e + 1], s2 = csrc[e + 2], s3 = csrc[e + 3];
    float wa = dinv[s0] * di, wb = dinv[s1] * di, wc = dinv[s2] * di, wd = dinv[s3] * di;
    float4 u0 = *(const float4*)(h + (size_t)s0 * 96 + c4);
    float4 u1 = *(const float4*)(h + (size_t)s1 * 96 + c4);
    float4 u2 = *(const float4*)(h + (size_t)s2 * 96 + c4);
    float4 u3 = *(const float4*)(h + (size_t)s3 * 96 + c4);
    acc.x += u0.x * wa + u1.x * wb + u2.x * wc + u3.x * wd;
    acc.y += u0.y * wa + u1.y * wb + u2.y * wc + u3.y * wd;
    acc.z += u0.z * wa + u1.z * wb + u2.z * wc + u3.z * wd;
    acc.w += u0.w * wa + u1.w * wb + u2.w * wc + u3.w * wd;
  }
  for (; e < e1; ++e) {
    int s = csrc[e];
    float w = dinv[s] * di;
    float4 u = *(const float4*)(h + (size_t)s * 96 + c4);
    acc.x += u.x * w; acc.y += u.y * w; acc.z += u.z * w; acc.w += u.w * w;
  }
  *(float4*)(agg + (size_t)n * 96 + c4) = acc;
}

__global__ void k_gather256(const int* __restrict__ off, const int* __restrict__ csrc,
                            const float* __restrict__ dinv, const float* __restrict__ h1,
                            float* __restrict__ agg) {
  int i = blockIdx.x * 256 + threadIdx.x;
  if (i >= N_GRID * 64) return;
  int n = i >> 6;
  int c4 = (i & 63) << 2;
  float di = dinv[n];
  float4 v = *(const float4*)(h1 + (size_t)n * 256 + c4);
  float w0 = di * di;
  float4 acc = make_float4(v.x * w0, v.y * w0, v.z * w0, v.w * w0);
  int e0 = off[n], e1 = off[n + 1];
  int e = e0;
  for (; e + 3 < e1; e += 4) {
    int s0 = csrc[e], s1 = csrc[e + 1], s2 = csrc[e + 2], s3 = csrc[e + 3];
    float wa = dinv[s0] * di, wb = dinv[s1] * di, wc = dinv[s2] * di, wd = dinv[s3] * di;
    float4 u0 = *(const float4*)(h1 + (size_t)s0 * 256 + c4);
    float4 u1 = *(const float4*)(h1 + (size_t)s1 * 256 + c4);
    float4 u2 = *(const float4*)(h1 + (size_t)s2 * 256 + c4);
    float4 u3 = *(const float4*)(h1 + (size_t)s3 * 256 + c4);
    acc.x += u0.x * wa + u1.x * wb + u2.x * wc + u3.x * wd;
    acc.y += u0.y * wa + u1.y * wb + u2.y * wc + u3.y * wd;
    acc.z += u0.z * wa + u1.z * wb + u2.z * wc + u3.z * wd;
    acc.w += u0.w * wa + u1.w * wb + u2.w * wc + u3.w * wd;
  }
  for (; e < e1; ++e) {
    int s = csrc[e];
    float w = dinv[s] * di;
    float4 u = *(const float4*)(h1 + (size_t)s * 256 + c4);
    acc.x += u.x * w; acc.y += u.y * w; acc.z += u.z * w; acc.w += u.w * w;
  }
  *(float4*)(agg + (size_t)n * 256 + c4) = acc;
}

// ---------------- GEMM1: 512-thread, BM=256 x BN=128, 8x8/thread, single-buffer, runtime-K ----------------
// Same per-thread body as the proven 256-thr kernel (76 VGPR, no spill) — only the block shape changes.
// 8 waves/block, 2 blocks/CU (24.9 KB LDS, ~80 VGPR) = 16 waves/CU = 4 waves/SIMD, 2x the latency
// hiding of round 8 (VALUBusy 49% @ 2 waves/SIMD). gelu+bias fused.
__global__ __launch_bounds__(512, 2) void k_gemm1(const float* __restrict__ A, const float* __restrict__ W,
                                                  const float* __restrict__ bias, float* __restrict__ C,
                                                  int M, int K, int N, int ldc) {
  constexpr int BM = 256, BN = 128, BK = 16;
  __shared__ float As[BK][BM + 1];   // 16.4 KB
  __shared__ float Ws[BK][BN + 4];   // 8.4 KB
  int t = threadIdx.x;
  int tx = t & 15, ty = t >> 4;      // tx 0..15 (cols), ty 0..31 (rows)
  int bm = blockIdx.y * BM, bn = blockIdx.x * BN;
  float acc[8][8] = {};
  for (int bk = 0; bk < K; bk += BK) {
#pragma unroll
    for (int it = 0; it < 2; ++it) {
      int idx = t + it * 512;              // 0..1023 over 256 rows x 4 float4
      int m = idx >> 2, k4 = (idx & 3) << 2;
      float4 v = make_float4(0.f, 0.f, 0.f, 0.f);
      if (bm + m < M) v = *(const float4*)(A + (size_t)(bm + m) * K + bk + k4);
      As[k4 + 0][m] = v.x;
      As[k4 + 1][m] = v.y;
      As[k4 + 2][m] = v.z;
      As[k4 + 3][m] = v.w;
    }
    {
      int idx = t;                          // 0..511 over 16 k x 32 float4
      int k = idx >> 5, j4 = (idx & 31) << 2;
      float4 v = make_float4(0.f, 0.f, 0.f, 0.f);
      if (bn + j4 + 3 < N) v = *(const float4*)(W + (size_t)(bk + k) * N + bn + j4);
      *(float4*)&Ws[k][j4] = v;
    }
    __syncthreads();
#pragma unroll
    for (int k = 0; k < BK; ++k) {
      float a[8], w[8];
      *(float4*)&a[0] = *(const float4*)&As[k][ty * 4];
      *(float4*)&a[4] = *(const float4*)&As[k][128 + ty * 4];
      *(float4*)&w[0] = *(const float4*)&Ws[k][tx * 4];
      *(float4*)&w[4] = *(const float4*)&Ws[k][64 + tx * 4];
#pragma unroll
      for (int i = 0; i < 8; ++i)
#pragma unroll
        for (int j = 0; j < 8; ++j)
          acc[i][j] += a[i] * w[j];
    }
    __syncthreads();
  }
#pragma unroll
  for (int i = 0; i < 8; ++i) {
    int gm = bm + ((i < 4) ? ty * 4 + i : 128 + ty * 4 + (i - 4));
    if (gm >= M) continue;
    float v[8];
#pragma unroll
    for (int j = 0; j < 8; ++j) {
      int gj = bn + ((j < 4) ? tx * 4 + j : 64 + tx * 4 + (j - 4));
      float x = acc[i][j];
      if (gj < N) x += bias[gj];
      x = 0.5f * x * (1.0f + erff(x * 0.70710678118654752f));
      v[j] = x;
    }
    int c0 = bn + tx * 4, c1 = bn + 64 + tx * 4;
    float* row = C + (size_t)gm * ldc;
    if (c0 + 3 < N) *(float4*)(row + c0) = make_float4(v[0], v[1], v[2], v[3]);
    else { for (int j = 0; j < 4; ++j) if (c0 + j < N) row[c0 + j] = v[j]; }
    if (c1 + 3 < N) *(float4*)(row + c1) = make_float4(v[4], v[5], v[6], v[7]);
    else { for (int j = 0; j < 4; ++j) if (c1 + j < N) row[c1 + j] = v[4 + j]; }
  }
}

// ---------------- fp32 tiled GEMM (round-5 proven config: 76 VGPR, no spill) ----------------
template<int ACT, bool TRANSC, bool BIAS>
__global__ __launch_bounds__(256, 2) void k_gemm(const float* __restrict__ A, const float* __restrict__ W,
                                                 const float* __restrict__ bias, float* __restrict__ C,
                                                 int M, int K, int N, int ldc) {
  constexpr int BM = 128, BN = 128, BK = 16;
  __shared__ float As[BK][BM + 1];   // stride 129: staging writes <=2-way
  __shared__ float Ws[BK][BN + 4];   // stride 132: reads at tx*4 / 64+tx*4 are 2-way (free)
  int t = threadIdx.x;
  int tx = t & 15, ty = t >> 4;
  int bm = blockIdx.y * BM, bn = blockIdx.x * BN;
  float acc[8][8] = {};
  for (int bk = 0; bk < K; bk += BK) {
#pragma unroll
    for (int it = 0; it < 2; ++it) {
      int idx = t + it * 256;              // 0..511 over 128 rows x 4 float4
      int m = idx >> 2, k4 = (idx & 3) << 2;
      float4 v = make_float4(0.f, 0.f, 0.f, 0.f);
      if (bm + m < M) v = *(const float4*)(A + (size_t)(bm + m) * K + bk + k4);
      As[k4 + 0][m] = v.x;
      As[k4 + 1][m] = v.y;
      As[k4 + 2][m] = v.z;
      As[k4 + 3][m] = v.w;
    }
#pragma unroll
    for (int it = 0; it < 2; ++it) {
      int idx = t + it * 256;              // 0..511 over 16 k x 32 float4
      int k = idx >> 5, j4 = (idx & 31) << 2;
      float4 v = make_float4(0.f, 0.f, 0.f, 0.f);
      if (bn + j4 + 3 < N) v = *(const float4*)(W + (size_t)(bk + k) * N + bn + j4);
      *(float4*)&Ws[k][j4] = v;
    }
    __syncthreads();
#pragma unroll
    for (int k = 0; k < BK; ++k) {
      float a[8], w[8];
      *(float4*)&a[0] = *(const float4*)&As[k][ty * 4];
      *(float4*)&a[4] = *(const float4*)&As[k][64 + ty * 4];
      *(float4*)&w[0] = *(const float4*)&Ws[k][tx * 4];
      *(float4*)&w[4] = *(const float4*)&Ws[k][64 + tx * 4];
#pragma unroll
      for (int i = 0; i < 8; ++i)
#pragma unroll
        for (int j = 0; j < 8; ++j)
          acc[i][j] += a[i] * w[j];
    }
    __syncthreads();
  }
  if (!TRANSC) {
#pragma unroll
    for (int i = 0; i < 8; ++i) {
      int gm = bm + ((i < 4) ? ty * 4 + i : 64 + ty * 4 + (i - 4));
      if (gm >= M) continue;
      float v[8];
#pragma unroll
      for (int j = 0; j < 8; ++j) {
        int gj = bn + ((j < 4) ? tx * 4 + j : 64 + tx * 4 + (j - 4));
        float x = acc[i][j];
        if (BIAS && gj < N) x += bias[gj];
        if (ACT) x = 0.5f * x * (1.0f + erff(x * 0.70710678118654752f));
        v[j] = x;
      }
      int c0 = bn + tx * 4, c1 = bn + 64 + tx * 4;
      float* row = C + (size_t)gm * ldc;
      if (c0 + 3 < N) *(float4*)(row + c0) = make_float4(v[0], v[1], v[2], v[3]);
      else { for (int j = 0; j < 4; ++j) if (c0 + j < N) row[c0 + j] = v[j]; }
      if (c1 + 3 < N) *(float4*)(row + c1) = make_float4(v[4], v[5], v[6], v[7]);
      else { for (int j = 0; j < 4; ++j) if (c1 + j < N) row[c1 + j] = v[4 + j]; }
    }
  } else {
#pragma unroll
    for (int j = 0; j < 8; ++j) {
      int gj = bn + ((j < 4) ? tx * 4 + j : 64 + tx * 4 + (j - 4));
      if (gj >= N) continue;
      float b = BIAS ? bias[gj] : 0.f;
      float v[8];
#pragma unroll
      for (int i = 0; i < 8; ++i) {
        float x = acc[i][j] + b;
        if (ACT) x = 0.5f * x * (1.0f + erff(x * 0.70710678118654752f));
        v[i] = x;
      }
      int r0 = bm + ty * 4, r1 = bm + 64 + ty * 4;
      float* col = C + (size_t)gj * ldc;
      if (r0 + 3 < M) *(float4*)(col + r0) = make_float4(v[0], v[1], v[2], v[3]);
      else { for (int i = 0; i < 4; ++i) if (r0 + i < M) col[r0 + i] = v[i]; }
      if (r1 + 3 < M) *(float4*)(col + r1) = make_float4(v[4], v[5], v[6], v[7]);
      else { for (int i = 0; i < 4; ++i) if (r1 + i < M) col[r1 + i] = v[4 + i]; }
    }
  }
}

// ---------------- bc = b2 @ T1 + bl1 @ Wl2 + bl2 ----------------
__global__ void k_bias_combine(const float* __restrict__ b2, const float* __restrict__ bl1,
                               const float* __restrict__ bl2, const float* __restrict__ T1,
                               const float* __restrict__ Wl2, float* __restrict__ bc) {
  int j = threadIdx.x;
  if (j >= OUT_CH) return;
  float s = bl2[j];
  for (int k = 0; k < HID; ++k)
    s += b2[k] * T1[k * OUT_CH + j] + bl1[k] * Wl2[k * OUT_CH + j];
  bc[j] = s;
}

extern "C" void kernel_launch(void* const* d_in, const int* in_sizes, int n_in,
                              void* d_out, int out_size, void* d_ws, size_t ws_size,
                              hipStream_t stream) {
  const float* xm  = (const float*)d_in[0];
  const float* xg  = (const float*)d_in[1];
  const int*   ei  = (const int*)d_in[2];
  const float* W1  = (const float*)d_in[3];
  const float* b1  = (const float*)d_in[4];
  const float* W2  = (const float*)d_in[5];
  const float* b2  = (const float*)d_in[6];
  const float* Wl1 = (const float*)d_in[7];
  const float* bl1 = (const float*)d_in[8];
  const float* Wl2 = (const float*)d_in[9];
  const float* bl2 = (const float*)d_in[10];
  float* out = (float*)d_out;

  // ---- workspace layout (floats); peak ~179.4 MB ----
  float* W0 = (float*)d_ws;
  const size_t MB = (size_t)N_GRID * 256;          // 16,680,960
  int*   deg  = (int*)(W0 + MB);
  int*   off  = deg + N_TOT;                       // N_TOT+1
  int*   cur  = off + N_TOT + 1;
  int*   bsum = cur + N_TOT;                       // 512
  int*   csrc = bsum + 512;                        // NE
  float* dinv = (float*)(csrc + NE);               // N_TOT
  float* T1   = dinv + N_TOT;                      // 256*96
  float* Wc   = T1 + HID * OUT_CH;                 // 256*96
  float* bc   = Wc + HID * OUT_CH;                 // 96
  size_t RH = MB + (size_t)4 * N_TOT + 1 + 512 + NE + 2 * HID * OUT_CH + 96;
  RH = (RH + 3) & ~(size_t)3;                      // 16B align
  float* h    = W0 + RH;
  float* h1   = W0 + RH;
  float* agg1 = W0;
  float* agg2 = W0;

  const int* esrc = ei;
  const int* edst = ei + NE;
  dim3 b256(256);
  const int NB_N = (N_TOT + 255) / 256;

  // t1. node features (N_TOT, 96)
  k_concat_transpose<<<dim3((N_TOT + 63) / 64), b256, 0, stream>>>(xg, xm, h);

  // t2. CSR by dst + dinv
  k_zeroi<<<dim3(NB_N), b256, 0, stream>>>(deg, N_TOT);
  k_hist<<<dim3((NE + 255) / 256), b256, 0, stream>>>(edst, deg);
  k_blocksum<<<dim3(NB_N), b256, 0, stream>>>(deg, bsum, N_TOT);
  k_scanbsum<<<dim3(1), dim3(512), 0, stream>>>(bsum, NB_N);
  k_offsets<<<dim3(NB_N), b256, 0, stream>>>(deg, bsum, off, cur, N_TOT);
  k_seti<<<dim3(1), dim3(1), 0, stream>>>(off + N_TOT, NE);
  k_fillcsr<<<dim3((NE + 255) / 256), b256, 0, stream>>>(esrc, edst, cur, csrc);
  k_dinv<<<dim3(NB_N), b256, 0, stream>>>(deg, dinv, N_TOT);

  // t3. agg1 = S @ h   (96 ch, gather)
  k_gather96<<<dim3((N_TOT * 24 + 255) / 256), b256, 0, stream>>>(off, csrc, dinv, h, agg1);

  // t4. h1 = gelu(agg1 @ W1 + b1)   (N_TOT, 256) — 512-thr BM=256 kernel
  k_gemm1<<<dim3(2, (N_TOT + 255) / 256), dim3(512), 0, stream>>>(agg1, W1, b1, h1, N_TOT, IN_CH, HID, HID);

  // t5-t7. combined tail weights: T1 = Wl1@Wl2; Wc = W2@T1; bc = b2@T1 + bl1@Wl2 + bl2
  k_gemm<0, false, false><<<dim3(1, 2), b256, 0, stream>>>(Wl1, Wl2, nullptr, T1, HID, HID, OUT_CH, OUT_CH);
  k_gemm<0, false, false><<<dim3(1, 2), b256, 0, stream>>>(W2, T1, nullptr, Wc, HID, HID, OUT_CH, OUT_CH);
  k_bias_combine<<<dim3(1), dim3(128), 0, stream>>>(b2, bl1, bl2, T1, Wl2, bc);

  // t8. agg2 = S @ h1 for dst < N_GRID   (256 ch, gather)
  k_gather256<<<dim3((N_GRID * 64 + 255) / 256), b256, 0, stream>>>(off, csrc, dinv, h1, agg2);

  // t9. out^T = (agg2 @ Wc + bc)^T   -> (96, N_GRID)
  k_gemm<0, true, true><<<dim3(1, (N_GRID + 127) / 128), b256, 0, stream>>>(agg2, Wc, bc, out, N_GRID, HID, OUT_CH, N_GRID);
}

// Round 10
// 469.010 us; speedup vs baseline: 1.0890x; 1.0890x over previous
//
#include <hip/hip_runtime.h>
#include <math.h>

#define N_GRID 65160
#define N_MESH 40962
#define N_TOT  106122
#define NE     521280
#define IN_CH  96
#define HID    256
#define OUT_CH 96

// ---------------- concat + transpose: (96,N) channel-major -> (N,96) node-major ----------------
__global__ void k_concat_transpose(const float* __restrict__ xg, const float* __restrict__ xm,
                                   float* __restrict__ h) {
  __shared__ float tile[IN_CH][65];
  int base = blockIdx.x * 64;
  int t = threadIdx.x;
#pragma unroll
  for (int it = 0; it < 24; ++it) {
    int lin = t + it * 256;            // 0..6143 over 96x64
    int c  = lin >> 6;
    int n0 = lin & 63;
    int n = base + n0;
    float v = 0.f;
    if (n < N_TOT) {
      v = (n < N_GRID) ? xg[(size_t)c * N_GRID + n]
                       : xm[(size_t)c * N_MESH + (n - N_GRID)];
    }
    tile[c][n0] = v;
  }
  __syncthreads();
#pragma unroll
  for (int it = 0; it < 24; ++it) {
    int lin = t + it * 256;
    int c  = lin % 96;
    int n0 = lin / 96;
    int n = base + n0;
    if (n < N_TOT) h[(size_t)n * IN_CH + c] = tile[c][n0];
  }
}

// ---------------- final transpose: tb (N_GRID,96) node-major -> out (96,N_GRID) ----------------
__global__ void k_transpose_out(const float* __restrict__ tb, float* __restrict__ out) {
  __shared__ float tile[IN_CH][65];
  int base = blockIdx.x * 64;
  int t = threadIdx.x;
#pragma unroll
  for (int it = 0; it < 24; ++it) {
    int lin = t + it * 256;            // over 64 nodes x 96 ch
    int c  = lin % 96;
    int n0 = lin / 96;
    int n = base + n0;
    if (n < N_GRID) tile[c][n0] = tb[(size_t)n * 96 + c];
  }
  __syncthreads();
#pragma unroll
  for (int it = 0; it < 24; ++it) {
    int lin = t + it * 256;
    int c  = lin >> 6;
    int n0 = lin & 63;
    int n = base + n0;
    if (n < N_GRID) out[(size_t)c * N_GRID + n] = tile[c][n0];
  }
}

// ---------------- CSR build ----------------
__global__ void k_zeroi(int* __restrict__ p, int n) {
  int i = blockIdx.x * 256 + threadIdx.x;
  if (i < n) p[i] = 0;
}
__global__ void k_seti(int* __restrict__ p, int v) { *p = v; }

__global__ void k_hist(const int* __restrict__ dst, int* __restrict__ deg) {
  int e = blockIdx.x * 256 + threadIdx.x;
  if (e < NE) atomicAdd(&deg[dst[e]], 1);
}

__global__ void k_blocksum(const int* __restrict__ deg, int* __restrict__ bsum, int n) {
  __shared__ int s[256];
  int i = blockIdx.x * 256 + threadIdx.x;
  s[threadIdx.x] = (i < n) ? deg[i] : 0;
  __syncthreads();
  for (int st = 128; st > 0; st >>= 1) {
    if (threadIdx.x < st) s[threadIdx.x] += s[threadIdx.x + st];
    __syncthreads();
  }
  if (threadIdx.x == 0) bsum[blockIdx.x] = s[0];
}

__global__ void k_scanbsum(int* __restrict__ bsum, int nb) {   // single block, 512 thr
  __shared__ int s[512];
  int t = threadIdx.x;
  int v = (t < nb) ? bsum[t] : 0;
  s[t] = v;
  __syncthreads();
  for (int off = 1; off < 512; off <<= 1) {
    int x = (t >= off) ? s[t - off] : 0;
    __syncthreads();
    s[t] += x;
    __syncthreads();
  }
  if (t < nb) bsum[t] = s[t] - v;   // exclusive
}

__global__ void k_offsets(const int* __restrict__ deg, const int* __restrict__ bsum,
                          int* __restrict__ off, int* __restrict__ cur, int n) {
  __shared__ int s[256];
  int i = blockIdx.x * 256 + threadIdx.x;
  int v = (i < n) ? deg[i] : 0;
  s[threadIdx.x] = v;
  __syncthreads();
  for (int o = 1; o < 256; o <<= 1) {
    int x = (threadIdx.x >= o) ? s[threadIdx.x - o] : 0;
    __syncthreads();
    s[threadIdx.x] += x;
    __syncthreads();
  }
  if (i < n) {
    int e = bsum[blockIdx.x] + s[threadIdx.x] - v;
    off[i] = e;
    cur[i] = e;
  }
}

__global__ void k_fillcsr(const int* __restrict__ src, const int* __restrict__ dst,
                          int* __restrict__ cur, int* __restrict__ csrc) {
  int e = blockIdx.x * 256 + threadIdx.x;
  if (e < NE) {
    int p = atomicAdd(&cur[dst[e]], 1);
    csrc[p] = src[e];
  }
}

__global__ void k_dinv(const int* __restrict__ deg, float* __restrict__ dinv, int n) {
  int i = blockIdx.x * 256 + threadIdx.x;
  if (i < n) dinv[i] = rsqrtf(1.0f + (float)deg[i]);
}

// ---------------- gather aggregation (no atomics), 4-edge unrolled ----------------
__global__ void k_gather96(const int* __restrict__ off, const int* __restrict__ csrc,
                           const float* __restrict__ dinv, const float* __restrict__ h,
                           float* __restrict__ agg) {
  int i = blockIdx.x * 256 + threadIdx.x;
  if (i >= N_TOT * 24) return;
  int n = i / 24;
  int c4 = (i % 24) << 2;
  float di = dinv[n];
  float4 v = *(const float4*)(h + (size_t)n * 96 + c4);
  float w0 = di * di;
  float4 acc = make_float4(v.x * w0, v.y * w0, v.z * w0, v.w * w0);
  int e0 = off[n], e1 = off[n + 1];
  int e = e0;
  for (; e + 3 < e1; e += 4) {
    int s0 = csrc[e], s1 = csrc[e + 1], s2 = csrc[e + 2], s3 = csrc[e + 3];
    float wa = dinv[s0] * di, wb = dinv[s1] * di, wc = dinv[s2] * di, wd = dinv[s3] * di;
    float4 u0 = *(const float4*)(h + (size_t)s0 * 96 + c4);
    float4 u1 = *(const float4*)(h + (size_t)s1 * 96 + c4);
    float4 u2 = *(const float4*)(h + (size_t)s2 * 96 + c4);
    float4 u3 = *(const float4*)(h + (size_t)s3 * 96 + c4);
    acc.x += u0.x * wa + u1.x * wb + u2.x * wc + u3.x * wd;
    acc.y += u0.y * wa + u1.y * wb + u2.y * wc + u3.y * wd;
    acc.z += u0.z * wa + u1.z * wb + u2.z * wc + u3.z * wd;
    acc.w += u0.w * wa + u1.w * wb + u2.w * wc + u3.w * wd;
  }
  for (; e < e1; ++e) {
    int s = csrc[e];
    float w = dinv[s] * di;
    float4 u = *(const float4*)(h + (size_t)s * 96 + c4);
    acc.x += u.x * w; acc.y += u.y * w; acc.z += u.z * w; acc.w += u.w * w;
  }
  *(float4*)(agg + (size_t)n * 96 + c4) = acc;
}

// gather over p (96 ch) for grid nodes only, + combined bias bc, write tb node-major
__global__ void k_gather96p(const int* __restrict__ off, const int* __restrict__ csrc,
                            const float* __restrict__ dinv, const float* __restrict__ p,
                            const float* __restrict__ bc, float* __restrict__ tb) {
  int i = blockIdx.x * 256 + threadIdx.x;
  if (i >= N_GRID * 24) return;
  int n = i / 24;
  int c4 = (i % 24) << 2;
  float di = dinv[n];
  float4 v = *(const float4*)(p + (size_t)n * 96 + c4);
  float w0 = di * di;
  float4 acc = make_float4(v.x * w0, v.y * w0, v.z * w0, v.w * w0);
  int e0 = off[n], e1 = off[n + 1];
  int e = e0;
  for (; e + 3 < e1; e += 4) {
    int s0 = csrc[e], s1 = csrc[e + 1], s2 = csrc[e + 2], s3 = csrc[e + 3];
    float wa = dinv[s0] * di, wb = dinv[s1] * di, wc = dinv[s2] * di, wd = dinv[s3] * di;
    float4 u0 = *(const float4*)(p + (size_t)s0 * 96 + c4);
    float4 u1 = *(const float4*)(p + (size_t)s1 * 96 + c4);
    float4 u2 = *(const float4*)(p + (size_t)s2 * 96 + c4);
    float4 u3 = *(const float4*)(p + (size_t)s3 * 96 + c4);
    acc.x += u0.x * wa + u1.x * wb + u2.x * wc + u3.x * wd;
    acc.y += u0.y * wa + u1.y * wb + u2.y * wc + u3.y * wd;
    acc.z += u0.z * wa + u1.z * wb + u2.z * wc + u3.z * wd;
    acc.w += u0.w * wa + u1.w * wb + u2.w * wc + u3.w * wd;
  }
  for (; e < e1; ++e) {
    int s = csrc[e];
    float w = dinv[s] * di;
    float4 u = *(const float4*)(p + (size_t)s * 96 + c4);
    acc.x += u.x * w; acc.y += u.y * w; acc.z += u.z * w; acc.w += u.w * w;
  }
  float4 b = *(const float4*)(bc + c4);
  acc.x += b.x; acc.y += b.y; acc.z += b.z; acc.w += b.w;
  *(float4*)(tb + (size_t)n * 96 + c4) = acc;
}

// ---------------- fp32 tiled GEMM (round-5 proven config: 76 VGPR, no spill) ----------------
template<int ACT, bool TRANSC, bool BIAS>
__global__ __launch_bounds__(256, 2) void k_gemm(const float* __restrict__ A, const float* __restrict__ W,
                                                 const float* __restrict__ bias, float* __restrict__ C,
                                                 int M, int K, int N, int ldc) {
  constexpr int BM = 128, BN = 128, BK = 16;
  __shared__ float As[BK][BM + 1];   // stride 129: staging writes <=2-way
  __shared__ float Ws[BK][BN + 4];   // stride 132: reads at tx*4 / 64+tx*4 are 2-way (free)
  int t = threadIdx.x;
  int tx = t & 15, ty = t >> 4;
  int bm = blockIdx.y * BM, bn = blockIdx.x * BN;
  float acc[8][8] = {};
  for (int bk = 0; bk < K; bk += BK) {
#pragma unroll
    for (int it = 0; it < 2; ++it) {
      int idx = t + it * 256;              // 0..511 over 128 rows x 4 float4
      int m = idx >> 2, k4 = (idx & 3) << 2;
      float4 v = make_float4(0.f, 0.f, 0.f, 0.f);
      if (bm + m < M) v = *(const float4*)(A + (size_t)(bm + m) * K + bk + k4);
      As[k4 + 0][m] = v.x;
      As[k4 + 1][m] = v.y;
      As[k4 + 2][m] = v.z;
      As[k4 + 3][m] = v.w;
    }
#pragma unroll
    for (int it = 0; it < 2; ++it) {
      int idx = t + it * 256;              // 0..511 over 16 k x 32 float4
      int k = idx >> 5, j4 = (idx & 31) << 2;
      float4 v = make_float4(0.f, 0.f, 0.f, 0.f);
      if (bn + j4 + 3 < N) v = *(const float4*)(W + (size_t)(bk + k) * N + bn + j4);
      *(float4*)&Ws[k][j4] = v;
    }
    __syncthreads();
#pragma unroll
    for (int k = 0; k < BK; ++k) {
      float a[8], w[8];
      *(float4*)&a[0] = *(const float4*)&As[k][ty * 4];
      *(float4*)&a[4] = *(const float4*)&As[k][64 + ty * 4];
      *(float4*)&w[0] = *(const float4*)&Ws[k][tx * 4];
      *(float4*)&w[4] = *(const float4*)&Ws[k][64 + tx * 4];
#pragma unroll
      for (int i = 0; i < 8; ++i)
#pragma unroll
        for (int j = 0; j < 8; ++j)
          acc[i][j] += a[i] * w[j];
    }
    __syncthreads();
  }
  if (!TRANSC) {
#pragma unroll
    for (int i = 0; i < 8; ++i) {
      int gm = bm + ((i < 4) ? ty * 4 + i : 64 + ty * 4 + (i - 4));
      if (gm >= M) continue;
      float v[8];
#pragma unroll
      for (int j = 0; j < 8; ++j) {
        int gj = bn + ((j < 4) ? tx * 4 + j : 64 + tx * 4 + (j - 4));
        float x = acc[i][j];
        if (BIAS && gj < N) x += bias[gj];
        if (ACT) x = 0.5f * x * (1.0f + erff(x * 0.70710678118654752f));
        v[j] = x;
      }
      int c0 = bn + tx * 4, c1 = bn + 64 + tx * 4;
      float* row = C + (size_t)gm * ldc;
      if (c0 + 3 < N) *(float4*)(row + c0) = make_float4(v[0], v[1], v[2], v[3]);
      else { for (int j = 0; j < 4; ++j) if (c0 + j < N) row[c0 + j] = v[j]; }
      if (c1 + 3 < N) *(float4*)(row + c1) = make_float4(v[4], v[5], v[6], v[7]);
      else { for (int j = 0; j < 4; ++j) if (c1 + j < N) row[c1 + j] = v[4 + j]; }
    }
  } else {
#pragma unroll
    for (int j = 0; j < 8; ++j) {
      int gj = bn + ((j < 4) ? tx * 4 + j : 64 + tx * 4 + (j - 4));
      if (gj >= N) continue;
      float b = BIAS ? bias[gj] : 0.f;
      float v[8];
#pragma unroll
      for (int i = 0; i < 8; ++i) {
        float x = acc[i][j] + b;
        if (ACT) x = 0.5f * x * (1.0f + erff(x * 0.70710678118654752f));
        v[i] = x;
      }
      int r0 = bm + ty * 4, r1 = bm + 64 + ty * 4;
      float* col = C + (size_t)gj * ldc;
      if (r0 + 3 < M) *(float4*)(col + r0) = make_float4(v[0], v[1], v[2], v[3]);
      else { for (int i = 0; i < 4; ++i) if (r0 + i < M) col[r0 + i] = v[i]; }
      if (r1 + 3 < M) *(float4*)(col + r1) = make_float4(v[4], v[5], v[6], v[7]);
      else { for (int i = 0; i < 4; ++i) if (r1 + i < M) col[r1 + i] = v[4 + i]; }
    }
  }
}

// ---------------- exact-width GEMM: C(M x 96) = A(M x K) @ W(K x 96), no wasted columns ----------------
// BM=128, BN=96, TN=6 (16 tx cover 96 cols exactly). Same staging/barrier structure as proven k_gemm.
// acc 48 + frags ~ 64 VGPR — under the (256,2) 128 cap, no spill expected (verify VGPR_Count).
__global__ __launch_bounds__(256, 2) void k_gemmN96(const float* __restrict__ A, const float* __restrict__ W,
                                                    float* __restrict__ C, int M, int K) {
  constexpr int BM = 128, BK = 16;
  __shared__ float As[BK][BM + 1];
  __shared__ float Ws[BK][100];        // 96 + 4 pad
  int t = threadIdx.x;
  int tx = t & 15, ty = t >> 4;
  int bm = blockIdx.x * BM;
  float acc[8][6] = {};
  for (int bk = 0; bk < K; bk += BK) {
#pragma unroll
    for (int it = 0; it < 2; ++it) {
      int idx = t + it * 256;              // 0..511 over 128 rows x 4 float4
      int m = idx >> 2, k4 = (idx & 3) << 2;
      float4 v = make_float4(0.f, 0.f, 0.f, 0.f);
      if (bm + m < M) v = *(const float4*)(A + (size_t)(bm + m) * K + bk + k4);
      As[k4 + 0][m] = v.x;
      As[k4 + 1][m] = v.y;
      As[k4 + 2][m] = v.z;
      As[k4 + 3][m] = v.w;
    }
#pragma unroll
    for (int it = 0; it < 2; ++it) {
      int idx = t + it * 256;              // need 384 tasks over 16 k x 24 float4
      if (idx < 384) {
        int k = idx / 24, j4 = (idx % 24) << 2;
        float4 v = *(const float4*)(W + (size_t)(bk + k) * 96 + j4);
        *(float4*)&Ws[k][j4] = v;
      }
    }
    __syncthreads();
#pragma unroll
    for (int k = 0; k < BK; ++k) {
      float a[8], w[6];
      *(float4*)&a[0] = *(const float4*)&As[k][ty * 4];
      *(float4*)&a[4] = *(const float4*)&As[k][64 + ty * 4];
      *(float2*)&w[0] = *(const float2*)&Ws[k][tx * 6];
      *(float2*)&w[2] = *(const float2*)&Ws[k][tx * 6 + 2];
      *(float2*)&w[4] = *(const float2*)&Ws[k][tx * 6 + 4];
#pragma unroll
      for (int i = 0; i < 8; ++i)
#pragma unroll
        for (int j = 0; j < 6; ++j)
          acc[i][j] += a[i] * w[j];
    }
    __syncthreads();
  }
#pragma unroll
  for (int i = 0; i < 8; ++i) {
    int gm = bm + ((i < 4) ? ty * 4 + i : 64 + ty * 4 + (i - 4));
    if (gm >= M) continue;
    float* row = C + (size_t)gm * 96 + tx * 6;
    *(float2*)(row + 0) = make_float2(acc[i][0], acc[i][1]);
    *(float2*)(row + 2) = make_float2(acc[i][2], acc[i][3]);
    *(float2*)(row + 4) = make_float2(acc[i][4], acc[i][5]);
  }
}

// ---------------- bc = b2 @ T1 + bl1 @ Wl2 + bl2 ----------------
__global__ void k_bias_combine(const float* __restrict__ b2, const float* __restrict__ bl1,
                               const float* __restrict__ bl2, const float* __restrict__ T1,
                               const float* __restrict__ Wl2, float* __restrict__ bc) {
  int j = threadIdx.x;
  if (j >= OUT_CH) return;
  float s = bl2[j];
  for (int k = 0; k < HID; ++k)
    s += b2[k] * T1[k * OUT_CH + j] + bl1[k] * Wl2[k * OUT_CH + j];
  bc[j] = s;
}

extern "C" void kernel_launch(void* const* d_in, const int* in_sizes, int n_in,
                              void* d_out, int out_size, void* d_ws, size_t ws_size,
                              hipStream_t stream) {
  const float* xm  = (const float*)d_in[0];
  const float* xg  = (const float*)d_in[1];
  const int*   ei  = (const int*)d_in[2];
  const float* W1  = (const float*)d_in[3];
  const float* b1  = (const float*)d_in[4];
  const float* W2  = (const float*)d_in[5];
  const float* b2  = (const float*)d_in[6];
  const float* Wl1 = (const float*)d_in[7];
  const float* bl1 = (const float*)d_in[8];
  const float* Wl2 = (const float*)d_in[9];
  const float* bl2 = (const float*)d_in[10];
  float* out = (float*)d_out;

  // ---- workspace layout (floats); peak ~179 MB ----
  // region0 [0, MB=16,680,960):  agg1 (t3-t4) [0,10.19M); p (t6-t7) [0,10.19M); tb (t7-t8) [10.19M,16.44M)
  // meta    [MB, ~MB+1M):        deg/off/cur/bsum/csrc/dinv/T1/Wc/bc  (t2..t7)
  // RH      [~MB+1M, +27.2M):    h (t1-t3) then h1 (t4-t6)
  float* W0 = (float*)d_ws;
  const size_t MB = (size_t)N_GRID * 256;          // 16,680,960
  int*   deg  = (int*)(W0 + MB);
  int*   off  = deg + N_TOT;                       // N_TOT+1
  int*   cur  = off + N_TOT + 1;
  int*   bsum = cur + N_TOT;                       // 512
  int*   csrc = bsum + 512;                        // NE
  float* dinv = (float*)(csrc + NE);               // N_TOT
  float* T1   = dinv + N_TOT;                      // 256*96
  float* Wc   = T1 + HID * OUT_CH;                 // 256*96
  float* bc   = Wc + HID * OUT_CH;                 // 96
  size_t RH = MB + (size_t)4 * N_TOT + 1 + 512 + NE + 2 * HID * OUT_CH + 96;
  RH = (RH + 3) & ~(size_t)3;                      // 16B align
  float* h    = W0 + RH;
  float* h1   = W0 + RH;
  float* agg1 = W0;
  float* p    = W0;                                // alias agg1 region (agg1 dead after t4)
  float* tb   = W0 + (size_t)N_TOT * 96;           // 10,187,712; +6,255,360 = 16,443,072 < MB

  const int* esrc = ei;
  const int* edst = ei + NE;
  dim3 b256(256);
  const int NB_N = (N_TOT + 255) / 256;

  // t1. node features (N_TOT, 96)
  k_concat_transpose<<<dim3((N_TOT + 63) / 64), b256, 0, stream>>>(xg, xm, h);

  // t2. CSR by dst + dinv
  k_zeroi<<<dim3(NB_N), b256, 0, stream>>>(deg, N_TOT);
  k_hist<<<dim3((NE + 255) / 256), b256, 0, stream>>>(edst, deg);
  k_blocksum<<<dim3(NB_N), b256, 0, stream>>>(deg, bsum, N_TOT);
  k_scanbsum<<<dim3(1), dim3(512), 0, stream>>>(bsum, NB_N);
  k_offsets<<<dim3(NB_N), b256, 0, stream>>>(deg, bsum, off, cur, N_TOT);
  k_seti<<<dim3(1), dim3(1), 0, stream>>>(off + N_TOT, NE);
  k_fillcsr<<<dim3((NE + 255) / 256), b256, 0, stream>>>(esrc, edst, cur, csrc);
  k_dinv<<<dim3(NB_N), b256, 0, stream>>>(deg, dinv, N_TOT);

  // t3. agg1 = S @ h   (96 ch, gather)
  k_gather96<<<dim3((N_TOT * 24 + 255) / 256), b256, 0, stream>>>(off, csrc, dinv, h, agg1);

  // t4. h1 = gelu(agg1 @ W1 + b1)   (N_TOT, 256) — proven 256-thr kernel
  k_gemm<1, false, true><<<dim3(2, (N_TOT + 127) / 128), b256, 0, stream>>>(agg1, W1, b1, h1, N_TOT, IN_CH, HID, HID);

  // t5. combined tail weights: T1 = Wl1@Wl2; Wc = W2@T1; bc = b2@T1 + bl1@Wl2 + bl2
  k_gemm<0, false, false><<<dim3(1, 2), b256, 0, stream>>>(Wl1, Wl2, nullptr, T1, HID, HID, OUT_CH, OUT_CH);
  k_gemm<0, false, false><<<dim3(1, 2), b256, 0, stream>>>(W2, T1, nullptr, Wc, HID, HID, OUT_CH, OUT_CH);
  k_bias_combine<<<dim3(1), dim3(128), 0, stream>>>(b2, bl1, bl2, T1, Wl2, bc);

  // t6. p = h1 @ Wc   (N_TOT, 96) — transform BEFORE aggregate: edge gather shrinks 1KB -> 384B/row
  k_gemmN96<<<dim3((N_TOT + 127) / 128), b256, 0, stream>>>(h1, Wc, p, N_TOT, HID);

  // t7. tb = S_grid @ p + bc   (96 ch, gather over grid-dst nodes only)
  k_gather96p<<<dim3((N_GRID * 24 + 255) / 256), b256, 0, stream>>>(off, csrc, dinv, p, bc, tb);

  // t8. out = tb^T   (96, N_GRID)
  k_transpose_out<<<dim3((N_GRID + 63) / 64), b256, 0, stream>>>(tb, out);
}

// Round 11
// 336.743 us; speedup vs baseline: 1.5168x; 1.3928x over previous
//
#include <hip/hip_runtime.h>
#include <math.h>

#define N_GRID 65160
#define N_MESH 40962
#define N_TOT  106122
#define NE     521280
#define IN_CH  96
#define HID    256
#define OUT_CH 96

typedef __attribute__((ext_vector_type(8))) short bf16x8;   // 8 bf16 in 4 VGPRs (guide §3)
typedef __attribute__((ext_vector_type(4))) float f32x4;

__device__ __forceinline__ unsigned short f2bf(float f) {   // fp32 -> bf16 RNE
  unsigned u = __float_as_uint(f);
  return (unsigned short)((u + 0x7FFFu + ((u >> 16) & 1u)) >> 16);
}
__device__ __forceinline__ float bf2f(unsigned short s) {
  return __uint_as_float(((unsigned)s) << 16);
}
__device__ __forceinline__ float4 ldbf4(const unsigned short* p) {
  ushort4 u = *(const ushort4*)p;
  return make_float4(bf2f(u.x), bf2f(u.y), bf2f(u.z), bf2f(u.w));
}

// ---------------- concat + transpose: (96,N) fp32 channel-major -> (N,96) bf16 node-major ----------------
__global__ void k_concat_transpose(const float* __restrict__ xg, const float* __restrict__ xm,
                                   unsigned short* __restrict__ h) {
  __shared__ float tile[IN_CH][65];
  int base = blockIdx.x * 64;
  int t = threadIdx.x;
#pragma unroll
  for (int it = 0; it < 24; ++it) {
    int lin = t + it * 256;            // 0..6143 over 96x64
    int c  = lin >> 6;
    int n0 = lin & 63;
    int n = base + n0;
    float v = 0.f;
    if (n < N_TOT) {
      v = (n < N_GRID) ? xg[(size_t)c * N_GRID + n]
                       : xm[(size_t)c * N_MESH + (n - N_GRID)];
    }
    tile[c][n0] = v;
  }
  __syncthreads();
#pragma unroll
  for (int it = 0; it < 24; ++it) {
    int lin = t + it * 256;
    int c  = lin % 96;
    int n0 = lin / 96;
    int n = base + n0;
    if (n < N_TOT) h[(size_t)n * IN_CH + c] = f2bf(tile[c][n0]);
  }
}

// ---------------- final transpose: tb (N_GRID,96) fp32 node-major -> out (96,N_GRID) ----------------
__global__ void k_transpose_out(const float* __restrict__ tb, float* __restrict__ out) {
  __shared__ float tile[IN_CH][65];
  int base = blockIdx.x * 64;
  int t = threadIdx.x;
#pragma unroll
  for (int it = 0; it < 24; ++it) {
    int lin = t + it * 256;
    int c  = lin % 96;
    int n0 = lin / 96;
    int n = base + n0;
    if (n < N_GRID) tile[c][n0] = tb[(size_t)n * 96 + c];
  }
  __syncthreads();
#pragma unroll
  for (int it = 0; it < 24; ++it) {
    int lin = t + it * 256;
    int c  = lin >> 6;
    int n0 = lin & 63;
    int n = base + n0;
    if (n < N_GRID) out[(size_t)c * N_GRID + n] = tile[c][n0];
  }
}

// ---------------- CSR build ----------------
__global__ void k_zeroi(int* __restrict__ p, int n) {
  int i = blockIdx.x * 256 + threadIdx.x;
  if (i < n) p[i] = 0;
}
__global__ void k_seti(int* __restrict__ p, int v) { *p = v; }

__global__ void k_hist(const int* __restrict__ dst, int* __restrict__ deg) {
  int e = blockIdx.x * 256 + threadIdx.x;
  if (e < NE) atomicAdd(&deg[dst[e]], 1);
}

__global__ void k_blocksum(const int* __restrict__ deg, int* __restrict__ bsum, int n) {
  __shared__ int s[256];
  int i = blockIdx.x * 256 + threadIdx.x;
  s[threadIdx.x] = (i < n) ? deg[i] : 0;
  __syncthreads();
  for (int st = 128; st > 0; st >>= 1) {
    if (threadIdx.x < st) s[threadIdx.x] += s[threadIdx.x + st];
    __syncthreads();
  }
  if (threadIdx.x == 0) bsum[blockIdx.x] = s[0];
}

__global__ void k_scanbsum(int* __restrict__ bsum, int nb) {   // single block, 512 thr
  __shared__ int s[512];
  int t = threadIdx.x;
  int v = (t < nb) ? bsum[t] : 0;
  s[t] = v;
  __syncthreads();
  for (int off = 1; off < 512; off <<= 1) {
    int x = (t >= off) ? s[t - off] : 0;
    __syncthreads();
    s[t] += x;
    __syncthreads();
  }
  if (t < nb) bsum[t] = s[t] - v;   // exclusive
}

__global__ void k_offsets(const int* __restrict__ deg, const int* __restrict__ bsum,
                          int* __restrict__ off, int* __restrict__ cur, int n) {
  __shared__ int s[256];
  int i = blockIdx.x * 256 + threadIdx.x;
  int v = (i < n) ? deg[i] : 0;
  s[threadIdx.x] = v;
  __syncthreads();
  for (int o = 1; o < 256; o <<= 1) {
    int x = (threadIdx.x >= o) ? s[threadIdx.x - o] : 0;
    __syncthreads();
    s[threadIdx.x] += x;
    __syncthreads();
  }
  if (i < n) {
    int e = bsum[blockIdx.x] + s[threadIdx.x] - v;
    off[i] = e;
    cur[i] = e;
  }
}

__global__ void k_fillcsr(const int* __restrict__ src, const int* __restrict__ dst,
                          int* __restrict__ cur, int* __restrict__ csrc) {
  int e = blockIdx.x * 256 + threadIdx.x;
  if (e < NE) {
    int p = atomicAdd(&cur[dst[e]], 1);
    csrc[p] = src[e];
  }
}

__global__ void k_dinv(const int* __restrict__ deg, float* __restrict__ dinv, int n) {
  int i = blockIdx.x * 256 + threadIdx.x;
  if (i < n) dinv[i] = rsqrtf(1.0f + (float)deg[i]);
}

// ---------------- gather over bf16 h (4-edge unrolled, fp32 accumulate, bf16 out) ----------------
__global__ void k_gather96(const int* __restrict__ off, const int* __restrict__ csrc,
                           const float* __restrict__ dinv, const unsigned short* __restrict__ h,
                           unsigned short* __restrict__ agg) {
  int i = blockIdx.x * 256 + threadIdx.x;
  if (i >= N_TOT * 24) return;
  int n = i / 24;
  int c4 = (i % 24) << 2;
  float di = dinv[n];
  float4 v = ldbf4(h + (size_t)n * 96 + c4);
  float w0 = di * di;
  float4 acc = make_float4(v.x * w0, v.y * w0, v.z * w0, v.w * w0);
  int e0 = off[n], e1 = off[n + 1];
  int e = e0;
  for (; e + 3 < e1; e += 4) {
    int s0 = csrc[e], s1 = csrc[e + 1], s2 = csrc[e + 2], s3 = csrc[e + 3];
    float wa = dinv[s0] * di, wb = dinv[s1] * di, wc = dinv[s2] * di, wd = dinv[s3] * di;
    float4 u0 = ldbf4(h + (size_t)s0 * 96 + c4);
    float4 u1 = ldbf4(h + (size_t)s1 * 96 + c4);
    float4 u2 = ldbf4(h + (size_t)s2 * 96 + c4);
    float4 u3 = ldbf4(h + (size_t)s3 * 96 + c4);
    acc.x += u0.x * wa + u1.x * wb + u2.x * wc + u3.x * wd;
    acc.y += u0.y * wa + u1.y * wb + u2.y * wc + u3.y * wd;
    acc.z += u0.z * wa + u1.z * wb + u2.z * wc + u3.z * wd;
    acc.w += u0.w * wa + u1.w * wb + u2.w * wc + u3.w * wd;
  }
  for (; e < e1; ++e) {
    int s = csrc[e];
    float w = dinv[s] * di;
    float4 u = ldbf4(h + (size_t)s * 96 + c4);
    acc.x += u.x * w; acc.y += u.y * w; acc.z += u.z * w; acc.w += u.w * w;
  }
  ushort4 o;
  o.x = f2bf(acc.x); o.y = f2bf(acc.y); o.z = f2bf(acc.z); o.w = f2bf(acc.w);
  *(ushort4*)(agg + (size_t)n * 96 + c4) = o;
}

// gather over p (fp32, 96 ch) for grid nodes only, + combined bias bc, write tb node-major fp32
__global__ void k_gather96p(const int* __restrict__ off, const int* __restrict__ csrc,
                            const float* __restrict__ dinv, const float* __restrict__ p,
                            const float* __restrict__ bc, float* __restrict__ tb) {
  int i = blockIdx.x * 256 + threadIdx.x;
  if (i >= N_GRID * 24) return;
  int n = i / 24;
  int c4 = (i % 24) << 2;
  float di = dinv[n];
  float4 v = *(const float4*)(p + (size_t)n * 96 + c4);
  float w0 = di * di;
  float4 acc = make_float4(v.x * w0, v.y * w0, v.z * w0, v.w * w0);
  int e0 = off[n], e1 = off[n + 1];
  int e = e0;
  for (; e + 3 < e1; e += 4) {
    int s0 = csrc[e], s1 = csrc[e + 1], s2 = csrc[e + 2], s3 = csrc[e + 3];
    float wa = dinv[s0] * di, wb = dinv[s1] * di, wc = dinv[s2] * di, wd = dinv[s3] * di;
    float4 u0 = *(const float4*)(p + (size_t)s0 * 96 + c4);
    float4 u1 = *(const float4*)(p + (size_t)s1 * 96 + c4);
    float4 u2 = *(const float4*)(p + (size_t)s2 * 96 + c4);
    float4 u3 = *(const float4*)(p + (size_t)s3 * 96 + c4);
    acc.x += u0.x * wa + u1.x * wb + u2.x * wc + u3.x * wd;
    acc.y += u0.y * wa + u1.y * wb + u2.y * wc + u3.y * wd;
    acc.z += u0.z * wa + u1.z * wb + u2.z * wc + u3.z * wd;
    acc.w += u0.w * wa + u1.w * wb + u2.w * wc + u3.w * wd;
  }
  for (; e < e1; ++e) {
    int s = csrc[e];
    float w = dinv[s] * di;
    float4 u = *(const float4*)(p + (size_t)s * 96 + c4);
    acc.x += u.x * w; acc.y += u.y * w; acc.z += u.z * w; acc.w += u.w * w;
  }
  float4 b = *(const float4*)(bc + c4);
  acc.x += b.x; acc.y += b.y; acc.z += b.z; acc.w += b.w;
  *(float4*)(tb + (size_t)n * 96 + c4) = acc;
}

// ---------------- fp32 tiled GEMM (kept for the tiny fp32 weight-combine GEMMs) ----------------
template<int ACT, bool TRANSC, bool BIAS>
__global__ __launch_bounds__(256, 2) void k_gemm(const float* __restrict__ A, const float* __restrict__ W,
                                                 const float* __restrict__ bias, float* __restrict__ C,
                                                 int M, int K, int N, int ldc) {
  constexpr int BM = 128, BN = 128, BK = 16;
  __shared__ float As[BK][BM + 1];
  __shared__ float Ws[BK][BN + 4];
  int t = threadIdx.x;
  int tx = t & 15, ty = t >> 4;
  int bm = blockIdx.y * BM, bn = blockIdx.x * BN;
  float acc[8][8] = {};
  for (int bk = 0; bk < K; bk += BK) {
#pragma unroll
    for (int it = 0; it < 2; ++it) {
      int idx = t + it * 256;
      int m = idx >> 2, k4 = (idx & 3) << 2;
      float4 v = make_float4(0.f, 0.f, 0.f, 0.f);
      if (bm + m < M) v = *(const float4*)(A + (size_t)(bm + m) * K + bk + k4);
      As[k4 + 0][m] = v.x;
      As[k4 + 1][m] = v.y;
      As[k4 + 2][m] = v.z;
      As[k4 + 3][m] = v.w;
    }
#pragma unroll
    for (int it = 0; it < 2; ++it) {
      int idx = t + it * 256;
      int k = idx >> 5, j4 = (idx & 31) << 2;
      float4 v = make_float4(0.f, 0.f, 0.f, 0.f);
      if (bn + j4 + 3 < N) v = *(const float4*)(W + (size_t)(bk + k) * N + bn + j4);
      *(float4*)&Ws[k][j4] = v;
    }
    __syncthreads();
#pragma unroll
    for (int k = 0; k < BK; ++k) {
      float a[8], w[8];
      *(float4*)&a[0] = *(const float4*)&As[k][ty * 4];
      *(float4*)&a[4] = *(const float4*)&As[k][64 + ty * 4];
      *(float4*)&w[0] = *(const float4*)&Ws[k][tx * 4];
      *(float4*)&w[4] = *(const float4*)&Ws[k][64 + tx * 4];
#pragma unroll
      for (int i = 0; i < 8; ++i)
#pragma unroll
        for (int j = 0; j < 8; ++j)
          acc[i][j] += a[i] * w[j];
    }
    __syncthreads();
  }
  if (!TRANSC) {
#pragma unroll
    for (int i = 0; i < 8; ++i) {
      int gm = bm + ((i < 4) ? ty * 4 + i : 64 + ty * 4 + (i - 4));
      if (gm >= M) continue;
      float v[8];
#pragma unroll
      for (int j = 0; j < 8; ++j) {
        int gj = bn + ((j < 4) ? tx * 4 + j : 64 + tx * 4 + (j - 4));
        float x = acc[i][j];
        if (BIAS && gj < N) x += bias[gj];
        if (ACT) x = 0.5f * x * (1.0f + erff(x * 0.70710678118654752f));
        v[j] = x;
      }
      int c0 = bn + tx * 4, c1 = bn + 64 + tx * 4;
      float* row = C + (size_t)gm * ldc;
      if (c0 + 3 < N) *(float4*)(row + c0) = make_float4(v[0], v[1], v[2], v[3]);
      else { for (int j = 0; j < 4; ++j) if (c0 + j < N) row[c0 + j] = v[j]; }
      if (c1 + 3 < N) *(float4*)(row + c1) = make_float4(v[4], v[5], v[6], v[7]);
      else { for (int j = 0; j < 4; ++j) if (c1 + j < N) row[c1 + j] = v[4 + j]; }
    }
  } else {
#pragma unroll
    for (int j = 0; j < 8; ++j) {
      int gj = bn + ((j < 4) ? tx * 4 + j : 64 + tx * 4 + (j - 4));
      if (gj >= N) continue;
      float b = BIAS ? bias[gj] : 0.f;
      float v[8];
#pragma unroll
      for (int i = 0; i < 8; ++i) {
        float x = acc[i][j] + b;
        if (ACT) x = 0.5f * x * (1.0f + erff(x * 0.70710678118654752f));
        v[i] = x;
      }
      int r0 = bm + ty * 4, r1 = bm + 64 + ty * 4;
      float* col = C + (size_t)gj * ldc;
      if (r0 + 3 < M) *(float4*)(col + r0) = make_float4(v[0], v[1], v[2], v[3]);
      else { for (int i = 0; i < 4; ++i) if (r0 + i < M) col[r0 + i] = v[i]; }
      if (r1 + 3 < M) *(float4*)(col + r1) = make_float4(v[4], v[5], v[6], v[7]);
      else { for (int i = 0; i < 4; ++i) if (r1 + i < M) col[r1 + i] = v[4 + i]; }
    }
  }
}

// ---------------- weight casts (fp32 -> bf16, transposed to col-major for B-fragment staging) ----------------
__global__ void k_cast_w1t(const float* __restrict__ W1, unsigned short* __restrict__ W1bt) {
  int idx = blockIdx.x * 256 + threadIdx.x;          // over [256 n][96 k]
  if (idx >= 256 * 96) return;
  int n = idx / 96, k = idx % 96;
  W1bt[idx] = f2bf(W1[(size_t)k * 256 + n]);
}
__global__ void k_cast_wct(const float* __restrict__ Wc, unsigned short* __restrict__ Wcbt) {
  int idx = blockIdx.x * 256 + threadIdx.x;          // over [96 n][256 k]
  if (idx >= 96 * 256) return;
  int n = idx / 256, k = idx % 256;
  Wcbt[idx] = f2bf(Wc[(size_t)k * 96 + n]);
}

// ---------------- MFMA GEMM1: h1 = gelu(agg1 @ W1 + b1), bf16 in, bf16 out ----------------
// BM=64 (4 waves x 16 rows), BN=64 (4 frags/wave), K=96 staged entirely -> ONE barrier per block.
// Frag maps (guide §3, m89-verified C/D): A: row=lane&15, k-slots=(lane>>4)*8+j; B symmetric; 
// D: col=lane&15, row=(lane>>4)*4+reg. LDS stride 104 (52 dw) -> 2-way reads (free, m136).
__global__ __launch_bounds__(256) void k_mgemm1(const unsigned short* __restrict__ A,
                                                const unsigned short* __restrict__ Bt,  // [256 n][96 k]
                                                const float* __restrict__ bias,
                                                unsigned short* __restrict__ C, int M) {
  __shared__ unsigned short As[64][104];
  __shared__ unsigned short Bs[64][104];
  int t = threadIdx.x;
  int bm = blockIdx.y * 64, bn = blockIdx.x * 64;
#pragma unroll
  for (int it = 0; it < 3; ++it) {                    // A: 64 rows x 12 groups of 8 bf16
    int idx = t + it * 256;
    int row = idx / 12, g = idx % 12;
    uint4 v = make_uint4(0u, 0u, 0u, 0u);
    if (bm + row < M) v = *(const uint4*)(A + (size_t)(bm + row) * 96 + g * 8);
    *(uint4*)&As[row][g * 8] = v;
  }
#pragma unroll
  for (int it = 0; it < 3; ++it) {                    // B: 64 cols x 12 groups
    int idx = t + it * 256;
    int n = idx / 12, g = idx % 12;
    uint4 v = *(const uint4*)(Bt + (size_t)(bn + n) * 96 + g * 8);
    *(uint4*)&Bs[n][g * 8] = v;
  }
  __syncthreads();
  int wave = t >> 6, lane = t & 63;
  int l15 = lane & 15, lhi = lane >> 4;
  f32x4 acc[4];
#pragma unroll
  for (int f = 0; f < 4; ++f) acc[f] = (f32x4){0.f, 0.f, 0.f, 0.f};
  int arow = wave * 16 + l15;
#pragma unroll
  for (int ks = 0; ks < 3; ++ks) {
    bf16x8 a = *(const bf16x8*)&As[arow][ks * 32 + lhi * 8];
#pragma unroll
    for (int f = 0; f < 4; ++f) {
      bf16x8 b = *(const bf16x8*)&Bs[f * 16 + l15][ks * 32 + lhi * 8];
      acc[f] = __builtin_amdgcn_mfma_f32_16x16x32_bf16(a, b, acc[f], 0, 0, 0);
    }
  }
#pragma unroll
  for (int f = 0; f < 4; ++f) {
    int col = bn + f * 16 + l15;
    float bv = bias[col];
#pragma unroll
    for (int r = 0; r < 4; ++r) {
      int row = bm + wave * 16 + lhi * 4 + r;
      if (row < M) {
        float x = acc[f][r] + bv;
        x = 0.5f * x * (1.0f + erff(x * 0.70710678118654752f));
        C[(size_t)row * 256 + col] = f2bf(x);
      }
    }
  }
}

// ---------------- MFMA GEMM2: p = h1 @ Wc, bf16 in, fp32 out ----------------
// BM=64, BN=96 (6 frags/wave), K=256 in 4 chunks of 64 (2 k-steps each). 23 KB LDS.
__global__ __launch_bounds__(256) void k_mgemmN96(const unsigned short* __restrict__ A,
                                                  const unsigned short* __restrict__ Bt, // [96 n][256 k]
                                                  float* __restrict__ P, int M) {
  __shared__ unsigned short As[64][72];
  __shared__ unsigned short Bs[96][72];
  int t = threadIdx.x;
  int bm = blockIdx.x * 64;
  int wave = t >> 6, lane = t & 63;
  int l15 = lane & 15, lhi = lane >> 4;
  f32x4 acc[6];
#pragma unroll
  for (int f = 0; f < 6; ++f) acc[f] = (f32x4){0.f, 0.f, 0.f, 0.f};
  for (int kc = 0; kc < 4; ++kc) {
#pragma unroll
    for (int it = 0; it < 2; ++it) {                  // A chunk: 64 rows x 8 groups
      int idx = t + it * 256;
      int row = idx >> 3, g = idx & 7;
      uint4 v = make_uint4(0u, 0u, 0u, 0u);
      if (bm + row < M) v = *(const uint4*)(A + (size_t)(bm + row) * 256 + kc * 64 + g * 8);
      *(uint4*)&As[row][g * 8] = v;
    }
#pragma unroll
    for (int it = 0; it < 3; ++it) {                  // B chunk: 96 cols x 8 groups
      int idx = t + it * 256;
      int n = idx >> 3, g = idx & 7;
      uint4 v = *(const uint4*)(Bt + (size_t)n * 256 + kc * 64 + g * 8);
      *(uint4*)&Bs[n][g * 8] = v;
    }
    __syncthreads();
#pragma unroll
    for (int ks = 0; ks < 2; ++ks) {
      bf16x8 a = *(const bf16x8*)&As[wave * 16 + l15][ks * 32 + lhi * 8];
#pragma unroll
      for (int f = 0; f < 6; ++f) {
        bf16x8 b = *(const bf16x8*)&Bs[f * 16 + l15][ks * 32 + lhi * 8];
        acc[f] = __builtin_amdgcn_mfma_f32_16x16x32_bf16(a, b, acc[f], 0, 0, 0);
      }
    }
    __syncthreads();
  }
#pragma unroll
  for (int f = 0; f < 6; ++f) {
    int col = f * 16 + l15;
#pragma unroll
    for (int r = 0; r < 4; ++r) {
      int row = bm + wave * 16 + lhi * 4 + r;
      if (row < M) P[(size_t)row * 96 + col] = acc[f][r];
    }
  }
}

// ---------------- bc = b2 @ T1 + bl1 @ Wl2 + bl2 ----------------
__global__ void k_bias_combine(const float* __restrict__ b2, const float* __restrict__ bl1,
                               const float* __restrict__ bl2, const float* __restrict__ T1,
                               const float* __restrict__ Wl2, float* __restrict__ bc) {
  int j = threadIdx.x;
  if (j >= OUT_CH) return;
  float s = bl2[j];
  for (int k = 0; k < HID; ++k)
    s += b2[k] * T1[k * OUT_CH + j] + bl1[k] * Wl2[k * OUT_CH + j];
  bc[j] = s;
}

extern "C" void kernel_launch(void* const* d_in, const int* in_sizes, int n_in,
                              void* d_out, int out_size, void* d_ws, size_t ws_size,
                              hipStream_t stream) {
  const float* xm  = (const float*)d_in[0];
  const float* xg  = (const float*)d_in[1];
  const int*   ei  = (const int*)d_in[2];
  const float* W1  = (const float*)d_in[3];
  const float* b1  = (const float*)d_in[4];
  const float* W2  = (const float*)d_in[5];
  const float* b2  = (const float*)d_in[6];
  const float* Wl1 = (const float*)d_in[7];
  const float* bl1 = (const float*)d_in[8];
  const float* Wl2 = (const float*)d_in[9];
  const float* bl2 = (const float*)d_in[10];
  float* out = (float*)d_out;

  // ---- workspace layout (float units) ----
  // region0 [0, MB): agg1b bf16 (t3-t4, 2.55M fl) / p fp32 (t6-t7, 10.19M fl); tb fp32 [10.19M, 16.44M)
  // meta [MB, RH): CSR + T1/Wc/bc fp32 + W1bt/Wcbt bf16
  // [RH, +13.6M): hb bf16 (t1-t3) then h1b bf16 (t4-t6)
  float* W0 = (float*)d_ws;
  const size_t MB = (size_t)N_GRID * 256;          // 16,680,960
  int*   deg  = (int*)(W0 + MB);
  int*   off  = deg + N_TOT;                       // N_TOT+1
  int*   cur  = off + N_TOT + 1;
  int*   bsum = cur + N_TOT;                       // 512
  int*   csrc = bsum + 512;                        // NE
  float* dinv = (float*)(csrc + NE);               // N_TOT
  float* T1   = dinv + N_TOT;                      // 256*96
  float* Wc   = T1 + HID * OUT_CH;                 // 256*96
  float* bc   = Wc + HID * OUT_CH;                 // 96
  unsigned short* W1bt = (unsigned short*)(bc + 96);   // 256x96 bf16
  unsigned short* Wcbt = W1bt + 256 * 96;              // 96x256 bf16
  size_t RH = MB + (size_t)4 * N_TOT + 1 + 512 + NE + 2 * HID * OUT_CH + 96 + 24576;
  RH = (RH + 3) & ~(size_t)3;                      // 16B align
  unsigned short* hb   = (unsigned short*)(W0 + RH);   // N_TOT x 96 bf16
  unsigned short* h1b  = (unsigned short*)(W0 + RH);   // N_TOT x 256 bf16 (h dead after t3)
  unsigned short* agg1b = (unsigned short*)W0;
  float* p  = W0;                                  // after agg1b dead
  float* tb = W0 + (size_t)N_TOT * 96;             // 10,187,712 .. 16,443,072 < MB

  const int* esrc = ei;
  const int* edst = ei + NE;
  dim3 b256(256);
  const int NB_N = (N_TOT + 255) / 256;

  // t1. node features (N_TOT, 96) bf16
  k_concat_transpose<<<dim3((N_TOT + 63) / 64), b256, 0, stream>>>(xg, xm, hb);

  // t2. CSR by dst + dinv; cast W1 (independent)
  k_zeroi<<<dim3(NB_N), b256, 0, stream>>>(deg, N_TOT);
  k_hist<<<dim3((NE + 255) / 256), b256, 0, stream>>>(edst, deg);
  k_blocksum<<<dim3(NB_N), b256, 0, stream>>>(deg, bsum, N_TOT);
  k_scanbsum<<<dim3(1), dim3(512), 0, stream>>>(bsum, NB_N);
  k_offsets<<<dim3(NB_N), b256, 0, stream>>>(deg, bsum, off, cur, N_TOT);
  k_seti<<<dim3(1), dim3(1), 0, stream>>>(off + N_TOT, NE);
  k_fillcsr<<<dim3((NE + 255) / 256), b256, 0, stream>>>(esrc, edst, cur, csrc);
  k_dinv<<<dim3(NB_N), b256, 0, stream>>>(deg, dinv, N_TOT);
  k_cast_w1t<<<dim3(96), b256, 0, stream>>>(W1, W1bt);

  // t3. agg1 = S @ h   (96 ch, gather, bf16)
  k_gather96<<<dim3((N_TOT * 24 + 255) / 256), b256, 0, stream>>>(off, csrc, dinv, hb, agg1b);

  // t4. h1 = gelu(agg1 @ W1 + b1)  — bf16 MFMA
  k_mgemm1<<<dim3(4, (N_TOT + 63) / 64), b256, 0, stream>>>(agg1b, W1bt, b1, h1b, N_TOT);

  // t5. combined tail weights in fp32: T1 = Wl1@Wl2; Wc = W2@T1; bc; cast Wc -> bf16^T
  k_gemm<0, false, false><<<dim3(1, 2), b256, 0, stream>>>(Wl1, Wl2, nullptr, T1, HID, HID, OUT_CH, OUT_CH);
  k_gemm<0, false, false><<<dim3(1, 2), b256, 0, stream>>>(W2, T1, nullptr, Wc, HID, HID, OUT_CH, OUT_CH);
  k_bias_combine<<<dim3(1), dim3(128), 0, stream>>>(b2, bl1, bl2, T1, Wl2, bc);
  k_cast_wct<<<dim3(96), b256, 0, stream>>>(Wc, Wcbt);

  // t6. p = h1 @ Wc   (N_TOT, 96) — bf16 MFMA, fp32 out
  k_mgemmN96<<<dim3((N_TOT + 63) / 64), b256, 0, stream>>>(h1b, Wcbt, p, N_TOT);

  // t7. tb = S_grid @ p + bc   (96 ch, fp32 gather)
  k_gather96p<<<dim3((N_GRID * 24 + 255) / 256), b256, 0, stream>>>(off, csrc, dinv, p, bc, tb);

  // t8. out = tb^T   (96, N_GRID)
  k_transpose_out<<<dim3((N_GRID + 63) / 64), b256, 0, stream>>>(tb, out);
}

// Round 12
// 263.537 us; speedup vs baseline: 1.9381x; 1.2778x over previous
//
#include <hip/hip_runtime.h>
#include <math.h>

#define N_GRID 65160
#define N_MESH 40962
#define N_TOT  106122
#define NE     521280
#define IN_CH  96
#define HID    256
#define OUT_CH 96

typedef __attribute__((ext_vector_type(8))) short bf16x8;   // 8 bf16 in 4 VGPRs (guide §3)
typedef __attribute__((ext_vector_type(4))) float f32x4;

__device__ __forceinline__ unsigned short f2bf(float f) {   // fp32 -> bf16 RNE
  unsigned u = __float_as_uint(f);
  return (unsigned short)((u + 0x7FFFu + ((u >> 16) & 1u)) >> 16);
}
__device__ __forceinline__ float bf2f(unsigned short s) {
  return __uint_as_float(((unsigned)s) << 16);
}
__device__ __forceinline__ float4 ldbf4(const unsigned short* p) {
  ushort4 u = *(const ushort4*)p;
  return make_float4(bf2f(u.x), bf2f(u.y), bf2f(u.z), bf2f(u.w));
}

// ---------------- concat + transpose: (96,N) fp32 channel-major -> (N,96) bf16 node-major ----------------
__global__ void k_concat_transpose(const float* __restrict__ xg, const float* __restrict__ xm,
                                   unsigned short* __restrict__ h) {
  __shared__ float tile[IN_CH][65];
  int base = blockIdx.x * 64;
  int t = threadIdx.x;
#pragma unroll
  for (int it = 0; it < 24; ++it) {
    int lin = t + it * 256;            // 0..6143 over 96x64
    int c  = lin >> 6;
    int n0 = lin & 63;
    int n = base + n0;
    float v = 0.f;
    if (n < N_TOT) {
      v = (n < N_GRID) ? xg[(size_t)c * N_GRID + n]
                       : xm[(size_t)c * N_MESH + (n - N_GRID)];
    }
    tile[c][n0] = v;
  }
  __syncthreads();
#pragma unroll
  for (int it = 0; it < 24; ++it) {
    int lin = t + it * 256;
    int c  = lin % 96;
    int n0 = lin / 96;
    int n = base + n0;
    if (n < N_TOT) h[(size_t)n * IN_CH + c] = f2bf(tile[c][n0]);
  }
}

// ---------------- final transpose: tb (N_GRID,96) fp32 node-major -> out (96,N_GRID) ----------------
__global__ void k_transpose_out(const float* __restrict__ tb, float* __restrict__ out) {
  __shared__ float tile[IN_CH][65];
  int base = blockIdx.x * 64;
  int t = threadIdx.x;
#pragma unroll
  for (int it = 0; it < 24; ++it) {
    int lin = t + it * 256;
    int c  = lin % 96;
    int n0 = lin / 96;
    int n = base + n0;
    if (n < N_GRID) tile[c][n0] = tb[(size_t)n * 96 + c];
  }
  __syncthreads();
#pragma unroll
  for (int it = 0; it < 24; ++it) {
    int lin = t + it * 256;
    int c  = lin >> 6;
    int n0 = lin & 63;
    int n = base + n0;
    if (n < N_GRID) out[(size_t)c * N_GRID + n] = tile[c][n0];
  }
}

// ---------------- CSR build ----------------
__global__ void k_zeroi(int* __restrict__ p, int n) {
  int i = blockIdx.x * 256 + threadIdx.x;
  if (i < n) p[i] = 0;
}
__global__ void k_seti(int* __restrict__ p, int v) { *p = v; }

__global__ void k_hist(const int* __restrict__ dst, int* __restrict__ deg) {
  int e = blockIdx.x * 256 + threadIdx.x;
  if (e < NE) atomicAdd(&deg[dst[e]], 1);
}

__global__ void k_blocksum(const int* __restrict__ deg, int* __restrict__ bsum, int n) {
  __shared__ int s[256];
  int i = blockIdx.x * 256 + threadIdx.x;
  s[threadIdx.x] = (i < n) ? deg[i] : 0;
  __syncthreads();
  for (int st = 128; st > 0; st >>= 1) {
    if (threadIdx.x < st) s[threadIdx.x] += s[threadIdx.x + st];
    __syncthreads();
  }
  if (threadIdx.x == 0) bsum[blockIdx.x] = s[0];
}

__global__ void k_scanbsum(int* __restrict__ bsum, int nb) {   // single block, 512 thr
  __shared__ int s[512];
  int t = threadIdx.x;
  int v = (t < nb) ? bsum[t] : 0;
  s[t] = v;
  __syncthreads();
  for (int off = 1; off < 512; off <<= 1) {
    int x = (t >= off) ? s[t - off] : 0;
    __syncthreads();
    s[t] += x;
    __syncthreads();
  }
  if (t < nb) bsum[t] = s[t] - v;   // exclusive
}

__global__ void k_offsets(const int* __restrict__ deg, const int* __restrict__ bsum,
                          int* __restrict__ off, int* __restrict__ cur, int n) {
  __shared__ int s[256];
  int i = blockIdx.x * 256 + threadIdx.x;
  int v = (i < n) ? deg[i] : 0;
  s[threadIdx.x] = v;
  __syncthreads();
  for (int o = 1; o < 256; o <<= 1) {
    int x = (threadIdx.x >= o) ? s[threadIdx.x - o] : 0;
    __syncthreads();
    s[threadIdx.x] += x;
    __syncthreads();
  }
  if (i < n) {
    int e = bsum[blockIdx.x] + s[threadIdx.x] - v;
    off[i] = e;
    cur[i] = e;
  }
}

__global__ void k_fillcsr(const int* __restrict__ src, const int* __restrict__ dst,
                          int* __restrict__ cur, int* __restrict__ csrc) {
  int e = blockIdx.x * 256 + threadIdx.x;
  if (e < NE) {
    int p = atomicAdd(&cur[dst[e]], 1);
    csrc[p] = src[e];
  }
}

__global__ void k_dinv(const int* __restrict__ deg, float* __restrict__ dinv, int n) {
  int i = blockIdx.x * 256 + threadIdx.x;
  if (i < n) dinv[i] = rsqrtf(1.0f + (float)deg[i]);
}

// ---------------- gather over bf16 h (4-edge unrolled, fp32 accumulate, bf16 out) ----------------
__global__ void k_gather96(const int* __restrict__ off, const int* __restrict__ csrc,
                           const float* __restrict__ dinv, const unsigned short* __restrict__ h,
                           unsigned short* __restrict__ agg) {
  int i = blockIdx.x * 256 + threadIdx.x;
  if (i >= N_TOT * 24) return;
  int n = i / 24;
  int c4 = (i % 24) << 2;
  float di = dinv[n];
  float4 v = ldbf4(h + (size_t)n * 96 + c4);
  float w0 = di * di;
  float4 acc = make_float4(v.x * w0, v.y * w0, v.z * w0, v.w * w0);
  int e0 = off[n], e1 = off[n + 1];
  int e = e0;
  for (; e + 3 < e1; e += 4) {
    int s0 = csrc[e], s1 = csrc[e + 1], s2 = csrc[e + 2], s3 = csrc[e + 3];
    float wa = dinv[s0] * di, wb = dinv[s1] * di, wc = dinv[s2] * di, wd = dinv[s3] * di;
    float4 u0 = ldbf4(h + (size_t)s0 * 96 + c4);
    float4 u1 = ldbf4(h + (size_t)s1 * 96 + c4);
    float4 u2 = ldbf4(h + (size_t)s2 * 96 + c4);
    float4 u3 = ldbf4(h + (size_t)s3 * 96 + c4);
    acc.x += u0.x * wa + u1.x * wb + u2.x * wc + u3.x * wd;
    acc.y += u0.y * wa + u1.y * wb + u2.y * wc + u3.y * wd;
    acc.z += u0.z * wa + u1.z * wb + u2.z * wc + u3.z * wd;
    acc.w += u0.w * wa + u1.w * wb + u2.w * wc + u3.w * wd;
  }
  for (; e < e1; ++e) {
    int s = csrc[e];
    float w = dinv[s] * di;
    float4 u = ldbf4(h + (size_t)s * 96 + c4);
    acc.x += u.x * w; acc.y += u.y * w; acc.z += u.z * w; acc.w += u.w * w;
  }
  ushort4 o;
  o.x = f2bf(acc.x); o.y = f2bf(acc.y); o.z = f2bf(acc.z); o.w = f2bf(acc.w);
  *(ushort4*)(agg + (size_t)n * 96 + c4) = o;
}

// gather over p (fp32, 96 ch) for grid nodes only, + combined bias bc, write tb node-major fp32
__global__ void k_gather96p(const int* __restrict__ off, const int* __restrict__ csrc,
                            const float* __restrict__ dinv, const float* __restrict__ p,
                            const float* __restrict__ bc, float* __restrict__ tb) {
  int i = blockIdx.x * 256 + threadIdx.x;
  if (i >= N_GRID * 24) return;
  int n = i / 24;
  int c4 = (i % 24) << 2;
  float di = dinv[n];
  float4 v = *(const float4*)(p + (size_t)n * 96 + c4);
  float w0 = di * di;
  float4 acc = make_float4(v.x * w0, v.y * w0, v.z * w0, v.w * w0);
  int e0 = off[n], e1 = off[n + 1];
  int e = e0;
  for (; e + 3 < e1; e += 4) {
    int s0 = csrc[e], s1 = csrc[e + 1], s2 = csrc[e + 2], s3 = csrc[e + 3];
    float wa = dinv[s0] * di, wb = dinv[s1] * di, wc = dinv[s2] * di, wd = dinv[s3] * di;
    float4 u0 = *(const float4*)(p + (size_t)s0 * 96 + c4);
    float4 u1 = *(const float4*)(p + (size_t)s1 * 96 + c4);
    float4 u2 = *(const float4*)(p + (size_t)s2 * 96 + c4);
    float4 u3 = *(const float4*)(p + (size_t)s3 * 96 + c4);
    acc.x += u0.x * wa + u1.x * wb + u2.x * wc + u3.x * wd;
    acc.y += u0.y * wa + u1.y * wb + u2.y * wc + u3.y * wd;
    acc.z += u0.z * wa + u1.z * wb + u2.z * wc + u3.z * wd;
    acc.w += u0.w * wa + u1.w * wb + u2.w * wc + u3.w * wd;
  }
  for (; e < e1; ++e) {
    int s = csrc[e];
    float w = dinv[s] * di;
    float4 u = *(const float4*)(p + (size_t)s * 96 + c4);
    acc.x += u.x * w; acc.y += u.y * w; acc.z += u.z * w; acc.w += u.w * w;
  }
  float4 b = *(const float4*)(bc + c4);
  acc.x += b.x; acc.y += b.y; acc.z += b.z; acc.w += b.w;
  *(float4*)(tb + (size_t)n * 96 + c4) = acc;
}

// ---------------- small-matrix weight GEMM: C(Mx96) = [A; bvec](MxK) @ B(Kx96) ----------------
// Rows 0..M-2 from A, row M-1 = bvec (bias folded in as an extra row). 32-row x 96-col blocks ->
// grid = ceil(M/32) = 9 for M=257: 9 CUs instead of the 2 the generic 128-tile kernel used
// (round-11 counters: 62 us at 0.085% occupancy). Each thread: 2 rows x 6 cols.
__global__ __launch_bounds__(256, 2) void k_wgemm96(const float* __restrict__ A, const float* __restrict__ bvec,
                                                    const float* __restrict__ B, float* __restrict__ C,
                                                    int M, int K) {
  __shared__ float As[64][33];    // [k][row], 32 rows + pad
  __shared__ float Bs[64][100];   // [k][col], 96 + pad (rows 400B -> 16B aligned)
  int t = threadIdx.x;
  int tx = t & 15, ty = t >> 4;
  int bm = blockIdx.x * 32;
  float acc[2][6] = {};
  for (int kc = 0; kc < K; kc += 64) {
#pragma unroll
    for (int it = 0; it < 2; ++it) {            // A chunk: 32 rows x 16 float4
      int idx = t + it * 256;
      int r = idx >> 4, k4 = (idx & 15) << 2;
      int gr = bm + r;
      float4 v = make_float4(0.f, 0.f, 0.f, 0.f);
      if (gr < M) {
        const float* src = (gr < M - 1) ? (A + (size_t)gr * K + kc + k4) : (bvec + kc + k4);
        v = *(const float4*)src;
      }
      As[k4 + 0][r] = v.x;
      As[k4 + 1][r] = v.y;
      As[k4 + 2][r] = v.z;
      As[k4 + 3][r] = v.w;
    }
#pragma unroll
    for (int it = 0; it < 6; ++it) {            // B chunk: 64 k x 24 float4
      int idx = t + it * 256;
      int k = idx / 24, j4 = (idx % 24) << 2;
      float4 v = *(const float4*)(B + (size_t)(kc + k) * 96 + j4);
      *(float4*)&Bs[k][j4] = v;
    }
    __syncthreads();
#pragma unroll
    for (int k = 0; k < 64; ++k) {
      float a0 = As[k][ty * 2], a1 = As[k][ty * 2 + 1];
      float w[6];
      *(float2*)&w[0] = *(const float2*)&Bs[k][tx * 6];
      *(float2*)&w[2] = *(const float2*)&Bs[k][tx * 6 + 2];
      *(float2*)&w[4] = *(const float2*)&Bs[k][tx * 6 + 4];
#pragma unroll
      for (int j = 0; j < 6; ++j) { acc[0][j] += a0 * w[j]; acc[1][j] += a1 * w[j]; }
    }
    __syncthreads();
  }
#pragma unroll
  for (int i = 0; i < 2; ++i) {
    int gr = bm + ty * 2 + i;
    if (gr >= M) continue;
    float* row = C + (size_t)gr * 96 + tx * 6;
    row[0] = acc[i][0]; row[1] = acc[i][1]; row[2] = acc[i][2];
    row[3] = acc[i][3]; row[4] = acc[i][4]; row[5] = acc[i][5];
  }
}

// bc[j] = P1[256][j] + P2[256][j] + bl2[j]
__global__ void k_bc_final(const float* __restrict__ r1, const float* __restrict__ r2,
                           const float* __restrict__ bl2, float* __restrict__ bc) {
  int j = threadIdx.x;
  if (j < OUT_CH) bc[j] = r1[j] + r2[j] + bl2[j];
}

// ---------------- weight casts (fp32 -> bf16, transposed to col-major for B-fragment staging) ----------------
__global__ void k_cast_w1t(const float* __restrict__ W1, unsigned short* __restrict__ W1bt) {
  int idx = blockIdx.x * 256 + threadIdx.x;          // over [256 n][96 k]
  if (idx >= 256 * 96) return;
  int n = idx / 96, k = idx % 96;
  W1bt[idx] = f2bf(W1[(size_t)k * 256 + n]);
}
__global__ void k_cast_wct(const float* __restrict__ Wc, unsigned short* __restrict__ Wcbt) {
  int idx = blockIdx.x * 256 + threadIdx.x;          // over [96 n][256 k]
  if (idx >= 96 * 256) return;
  int n = idx / 256, k = idx % 256;
  Wcbt[idx] = f2bf(Wc[(size_t)k * 96 + n]);
}

// ---------------- MFMA GEMM1: h1 = gelu(agg1 @ W1 + b1), bf16 in, bf16 out ----------------
// BM=64 (4 waves x 16 rows), BN=64 (4 frags/wave), K=96 staged entirely -> ONE barrier per block.
// Frag maps (guide §3, m89-verified C/D): D: col=lane&15, row=(lane>>4)*4+reg.
__global__ __launch_bounds__(256) void k_mgemm1(const unsigned short* __restrict__ A,
                                                const unsigned short* __restrict__ Bt,  // [256 n][96 k]
                                                const float* __restrict__ bias,
                                                unsigned short* __restrict__ C, int M) {
  __shared__ unsigned short As[64][104];
  __shared__ unsigned short Bs[64][104];
  int t = threadIdx.x;
  int bm = blockIdx.y * 64, bn = blockIdx.x * 64;
#pragma unroll
  for (int it = 0; it < 3; ++it) {                    // A: 64 rows x 12 groups of 8 bf16
    int idx = t + it * 256;
    int row = idx / 12, g = idx % 12;
    uint4 v = make_uint4(0u, 0u, 0u, 0u);
    if (bm + row < M) v = *(const uint4*)(A + (size_t)(bm + row) * 96 + g * 8);
    *(uint4*)&As[row][g * 8] = v;
  }
#pragma unroll
  for (int it = 0; it < 3; ++it) {                    // B: 64 cols x 12 groups
    int idx = t + it * 256;
    int n = idx / 12, g = idx % 12;
    uint4 v = *(const uint4*)(Bt + (size_t)(bn + n) * 96 + g * 8);
    *(uint4*)&Bs[n][g * 8] = v;
  }
  __syncthreads();
  int wave = t >> 6, lane = t & 63;
  int l15 = lane & 15, lhi = lane >> 4;
  f32x4 acc[4];
#pragma unroll
  for (int f = 0; f < 4; ++f) acc[f] = (f32x4){0.f, 0.f, 0.f, 0.f};
  int arow = wave * 16 + l15;
#pragma unroll
  for (int ks = 0; ks < 3; ++ks) {
    bf16x8 a = *(const bf16x8*)&As[arow][ks * 32 + lhi * 8];
#pragma unroll
    for (int f = 0; f < 4; ++f) {
      bf16x8 b = *(const bf16x8*)&Bs[f * 16 + l15][ks * 32 + lhi * 8];
      acc[f] = __builtin_amdgcn_mfma_f32_16x16x32_bf16(a, b, acc[f], 0, 0, 0);
    }
  }
#pragma unroll
  for (int f = 0; f < 4; ++f) {
    int col = bn + f * 16 + l15;
    float bv = bias[col];
#pragma unroll
    for (int r = 0; r < 4; ++r) {
      int row = bm + wave * 16 + lhi * 4 + r;
      if (row < M) {
        float x = acc[f][r] + bv;
        x = 0.5f * x * (1.0f + erff(x * 0.70710678118654752f));
        C[(size_t)row * 256 + col] = f2bf(x);
      }
    }
  }
}

// ---------------- MFMA GEMM2: p = h1 @ Wc, bf16 in, fp32 out ----------------
// BM=64, BN=96 (6 frags/wave), K=256 in 4 chunks of 64 (2 k-steps each). 23 KB LDS.
__global__ __launch_bounds__(256) void k_mgemmN96(const unsigned short* __restrict__ A,
                                                  const unsigned short* __restrict__ Bt, // [96 n][256 k]
                                                  float* __restrict__ P, int M) {
  __shared__ unsigned short As[64][72];
  __shared__ unsigned short Bs[96][72];
  int t = threadIdx.x;
  int bm = blockIdx.x * 64;
  int wave = t >> 6, lane = t & 63;
  int l15 = lane & 15, lhi = lane >> 4;
  f32x4 acc[6];
#pragma unroll
  for (int f = 0; f < 6; ++f) acc[f] = (f32x4){0.f, 0.f, 0.f, 0.f};
  for (int kc = 0; kc < 4; ++kc) {
#pragma unroll
    for (int it = 0; it < 2; ++it) {                  // A chunk: 64 rows x 8 groups
      int idx = t + it * 256;
      int row = idx >> 3, g = idx & 7;
      uint4 v = make_uint4(0u, 0u, 0u, 0u);
      if (bm + row < M) v = *(const uint4*)(A + (size_t)(bm + row) * 256 + kc * 64 + g * 8);
      *(uint4*)&As[row][g * 8] = v;
    }
#pragma unroll
    for (int it = 0; it < 3; ++it) {                  // B chunk: 96 cols x 8 groups
      int idx = t + it * 256;
      int n = idx >> 3, g = idx & 7;
      uint4 v = *(const uint4*)(Bt + (size_t)n * 256 + kc * 64 + g * 8);
      *(uint4*)&Bs[n][g * 8] = v;
    }
    __syncthreads();
#pragma unroll
    for (int ks = 0; ks < 2; ++ks) {
      bf16x8 a = *(const bf16x8*)&As[wave * 16 + l15][ks * 32 + lhi * 8];
#pragma unroll
      for (int f = 0; f < 6; ++f) {
        bf16x8 b = *(const bf16x8*)&Bs[f * 16 + l15][ks * 32 + lhi * 8];
        acc[f] = __builtin_amdgcn_mfma_f32_16x16x32_bf16(a, b, acc[f], 0, 0, 0);
      }
    }
    __syncthreads();
  }
#pragma unroll
  for (int f = 0; f < 6; ++f) {
    int col = f * 16 + l15;
#pragma unroll
    for (int r = 0; r < 4; ++r) {
      int row = bm + wave * 16 + lhi * 4 + r;
      if (row < M) P[(size_t)row * 96 + col] = acc[f][r];
    }
  }
}

extern "C" void kernel_launch(void* const* d_in, const int* in_sizes, int n_in,
                              void* d_out, int out_size, void* d_ws, size_t ws_size,
                              hipStream_t stream) {
  const float* xm  = (const float*)d_in[0];
  const float* xg  = (const float*)d_in[1];
  const int*   ei  = (const int*)d_in[2];
  const float* W1  = (const float*)d_in[3];
  const float* b1  = (const float*)d_in[4];
  const float* W2  = (const float*)d_in[5];
  const float* b2  = (const float*)d_in[6];
  const float* Wl1 = (const float*)d_in[7];
  const float* bl1 = (const float*)d_in[8];
  const float* Wl2 = (const float*)d_in[9];
  const float* bl2 = (const float*)d_in[10];
  float* out = (float*)d_out;

  // ---- workspace layout (float units) ----
  // region0 [0, MB): agg1b bf16 (t3-t4) / p fp32 (t6-t7); tb fp32 [10.19M, 16.44M)
  // meta [MB, RH): CSR + P1/P2 (257x96 each, 16B-aligned) + bc + W1bt/Wcbt bf16 (16B-aligned)
  // [RH, ...): hb bf16 (t1-t3) then h1b bf16 (t4-t6)
  float* W0 = (float*)d_ws;
  const size_t MB = (size_t)N_GRID * 256;          // 16,680,960
  int*   deg  = (int*)(W0 + MB);
  int*   off  = deg + N_TOT;                       // N_TOT+1
  int*   cur  = off + N_TOT + 1;
  int*   bsum = cur + N_TOT;                       // 512
  int*   csrc = bsum + 512;                        // NE
  float* dinv = (float*)(csrc + NE);               // N_TOT
  size_t p1off = ((size_t)(dinv + N_TOT - W0) + 3) & ~(size_t)3;   // 16B align
  float* P1 = W0 + p1off;                          // 257*96: [Wl1;bl1]@Wl2 (rows 0..255 = T1)
  float* P2 = P1 + 257 * 96;                       // 257*96: [W2;b2]@T1  (rows 0..255 = Wc)
  float* bc = P2 + 257 * 96;                       // 96
  size_t wboff = ((size_t)(bc + 96 - W0) + 3) & ~(size_t)3;        // 16B align
  unsigned short* W1bt = (unsigned short*)(W0 + wboff);            // 256x96 bf16
  unsigned short* Wcbt = W1bt + 256 * 96;                          // 96x256 bf16
  size_t RH = wboff + 24576 / 2 * 2;               // two bf16 arrays = 24576 floats
  RH = (RH + 24576 + 3) & ~(size_t)3;
  unsigned short* hb   = (unsigned short*)(W0 + RH);   // N_TOT x 96 bf16
  unsigned short* h1b  = (unsigned short*)(W0 + RH);   // N_TOT x 256 bf16 (hb dead after t3)
  unsigned short* agg1b = (unsigned short*)W0;
  float* p  = W0;                                  // after agg1b dead
  float* tb = W0 + (size_t)N_TOT * 96;             // 10,187,712 .. 16,443,072 < MB

  const int* esrc = ei;
  const int* edst = ei + NE;
  dim3 b256(256);
  const int NB_N = (N_TOT + 255) / 256;

  // t1. node features (N_TOT, 96) bf16
  k_concat_transpose<<<dim3((N_TOT + 63) / 64), b256, 0, stream>>>(xg, xm, hb);

  // t2. CSR by dst + dinv; cast W1 (independent)
  k_zeroi<<<dim3(NB_N), b256, 0, stream>>>(deg, N_TOT);
  k_hist<<<dim3((NE + 255) / 256), b256, 0, stream>>>(edst, deg);
  k_blocksum<<<dim3(NB_N), b256, 0, stream>>>(deg, bsum, N_TOT);
  k_scanbsum<<<dim3(1), dim3(512), 0, stream>>>(bsum, NB_N);
  k_offsets<<<dim3(NB_N), b256, 0, stream>>>(deg, bsum, off, cur, N_TOT);
  k_seti<<<dim3(1), dim3(1), 0, stream>>>(off + N_TOT, NE);
  k_fillcsr<<<dim3((NE + 255) / 256), b256, 0, stream>>>(esrc, edst, cur, csrc);
  k_dinv<<<dim3(NB_N), b256, 0, stream>>>(deg, dinv, N_TOT);
  k_cast_w1t<<<dim3(96), b256, 0, stream>>>(W1, W1bt);

  // t3. agg1 = S @ h   (96 ch, gather, bf16)
  k_gather96<<<dim3((N_TOT * 24 + 255) / 256), b256, 0, stream>>>(off, csrc, dinv, hb, agg1b);

  // t4. h1 = gelu(agg1 @ W1 + b1)  — bf16 MFMA
  k_mgemm1<<<dim3(4, (N_TOT + 63) / 64), b256, 0, stream>>>(agg1b, W1bt, b1, h1b, N_TOT);

  // t5. combined tail weights, now parallel (9 blocks each, was 2):
  //     P1 = [Wl1;bl1]@Wl2; P2 = [W2;b2]@T1; bc = P1[256]+P2[256]+bl2; cast Wc=P2[0:256] -> bf16^T
  k_wgemm96<<<dim3(9), b256, 0, stream>>>(Wl1, bl1, Wl2, P1, 257, HID);
  k_wgemm96<<<dim3(9), b256, 0, stream>>>(W2, b2, P1, P2, 257, HID);
  k_bc_final<<<dim3(1), dim3(96), 0, stream>>>(P1 + 256 * 96, P2 + 256 * 96, bl2, bc);
  k_cast_wct<<<dim3(96), b256, 0, stream>>>(P2, Wcbt);

  // t6. p = h1 @ Wc   (N_TOT, 96) — bf16 MFMA, fp32 out
  k_mgemmN96<<<dim3((N_TOT + 63) / 64), b256, 0, stream>>>(h1b, Wcbt, p, N_TOT);

  // t7. tb = S_grid @ p + bc   (96 ch, fp32 gather)
  k_gather96p<<<dim3((N_GRID * 24 + 255) / 256), b256, 0, stream>>>(off, csrc, dinv, p, bc, tb);

  // t8. out = tb^T   (96, N_GRID)
  k_transpose_out<<<dim3((N_GRID + 63) / 64), b256, 0, stream>>>(tb, out);
}